// Round 1
// baseline (30857.758 us; speedup 1.0000x reference)
//
#include <hip/hip_runtime.h>
#include <math.h>

// ---------------------------------------------------------------------------
// RITS forward, persistent-kernel baseline (fp32 VALU, custom grid barrier).
// B=256, L=256, D=128, H=256.
// Phase structure per step t (3 grid barriers/step):
//   P2: gates_h = hd @ W_hh^T   (interleaved store [b][j][q])
//       x_h = hd @ hist_W^T + b ; x_c = m*x + (1-m)*x_h     (+ alpha(0) at t=0)
//   P3: z_h = x_c @ Wf^T + fb ; c_h ; c_c ; out write ; loss partial
//       gamma_h(t+1), gamma_x(t+1)          (input-only, off critical path)
//   P4: gates = [c_c,m] @ W_ih^T + bias + gates_h ; LSTM
//       hd = o*tanh(c)*gamma_h(t+1)  (store h pre-decayed) ; alpha(t+1)
// ---------------------------------------------------------------------------

namespace {
constexpr int Bn = 256, Ln = 256, Dn = 128, Hn = 256;
constexpr int LD = Ln * Dn;  // 32768: stride per batch row in (B,L,D) tensors

// workspace layout (float offsets)
constexpr int OFF_LOSS  = 1;
constexpr int OFF_HD    = 64;                    // decayed h, (B,H)
constexpr int OFF_C     = OFF_HD + Bn * Hn;      // 65600 : LSTM cell, (B,H)
constexpr int OFF_G     = OFF_C + Bn * Hn;       // 131136: gamma_h(t+1), (B,H)
constexpr int OFF_GX    = OFF_G + Bn * Hn;       // 196672: gamma_x, (B,D)
constexpr int OFF_AL    = OFF_GX + Bn * Dn;      // 229440: alpha, (B,D)
constexpr int OFF_XH    = OFF_AL + Bn * Dn;      // 262208: x_h, (B,D)
constexpr int OFF_XC    = OFF_XH + Bn * Dn;      // 294976: x_c, (B,D)
constexpr int OFF_CC    = OFF_XC + Bn * Dn;      // 327744: c_c, (B,D)
constexpr int OFF_GH    = OFF_CC + Bn * Dn;      // 360512: gates_h [b][j][q], (B,4H)
constexpr int OFF_DEN   = OFF_GH + Bn * 4 * Hn;  // 622656: per-step denom, (L)
constexpr int OFF_TDHT  = OFF_DEN + Ln;          // 622912: td_h_W^T  [k<128][h<256]
constexpr int OFF_WCT   = OFF_TDHT + Dn * Hn;    // 655680: wc_W^T    [k<256][d<128]
constexpr int OFF_HISTT = OFF_WCT + 2 * Dn * Dn; // 688448: hist_W^T  [k<256][d<128]
constexpr int OFF_WFT   = OFF_HISTT + Hn * Dn;   // 721216: Wf^T (diag=0) [k<128][d<128]
constexpr int OFF_W4    = OFF_WFT + Dn * Dn;     // 737600: W_ih interleaved [k<256][j<256][q<4]
constexpr int OFF_WHHT  = OFF_W4 + 4 * Hn * 2 * Dn;   // 999744: W_hh^T [k<256][gc<1024]
constexpr int OFF_B4    = OFF_WHHT + 4 * Hn * Hn;     // 1261888: (b_ih+b_hh) interleaved [j][q]
constexpr int WS_FLOATS = OFF_B4 + 4 * Hn;            // 1262912 floats (~4.8 MB)
constexpr int ZERO_FLOATS = OFF_HD + 2 * Bn * Hn;     // counter+loss+hd+c must start at 0
}  // namespace

// -------------------- grid barrier (monotonic counter) ---------------------
__device__ __forceinline__ void gridbar(unsigned* cnt, unsigned target) {
  __syncthreads();
  if (threadIdx.x == 0) {
    __threadfence();  // release all prior writes (agent scope)
    __hip_atomic_fetch_add(cnt, 1u, __ATOMIC_RELAXED, __HIP_MEMORY_SCOPE_AGENT);
    while (__hip_atomic_load(cnt, __ATOMIC_RELAXED, __HIP_MEMORY_SCOPE_AGENT) < target)
      __builtin_amdgcn_s_sleep(1);
    __threadfence();  // acquire
  }
  __syncthreads();
}

// -------------------- one-time weight re-layout ----------------------------
__global__ void rits_prep(const float* __restrict__ td_h_W,
                          const float* __restrict__ wc_W,
                          const float* __restrict__ hist_W,
                          const float* __restrict__ feat_W,
                          const float* __restrict__ W_ih,
                          const float* __restrict__ W_hh,
                          const float* __restrict__ b_ih,
                          const float* __restrict__ b_hh,
                          float* __restrict__ ws) {
  int i = blockIdx.x * blockDim.x + threadIdx.x;
  if (i < 32768) {                       // tdhT [k][h] = td_h_W[h][k]
    int k = i >> 8, h = i & 255;
    ws[OFF_TDHT + i] = td_h_W[h * 128 + k];
    return;
  }
  i -= 32768;
  if (i < 32768) {                       // wcT [k][d] = wc_W[d][k]
    int k = i >> 7, d = i & 127;
    ws[OFF_WCT + i] = wc_W[d * 256 + k];
    return;
  }
  i -= 32768;
  if (i < 32768) {                       // histT [k][d] = hist_W[d][k]
    int k = i >> 7, d = i & 127;
    ws[OFF_HISTT + i] = hist_W[d * 256 + k];
    return;
  }
  i -= 32768;
  if (i < 16384) {                       // WfT [k][d] = feat_W[d][k], diag->0
    int k = i >> 7, d = i & 127;
    ws[OFF_WFT + i] = (d == k) ? 0.f : feat_W[d * 128 + k];
    return;
  }
  i -= 16384;
  if (i < 262144) {                      // W4 [k][j][q] = W_ih[q*256+j][k]
    int k = i >> 10, j = (i >> 2) & 255, q = i & 3;
    ws[OFF_W4 + i] = W_ih[(q * 256 + j) * 256 + k];
    return;
  }
  i -= 262144;
  if (i < 262144) {                      // WhhT [k][gc] = W_hh[gc][k]
    int k = i >> 10, gc = i & 1023;
    ws[OFF_WHHT + i] = W_hh[gc * 256 + k];
    return;
  }
  i -= 262144;
  if (i < 1024) {                        // bias4 [j][q]
    int j = i >> 2, q = i & 3;
    ws[OFF_B4 + i] = b_ih[q * 256 + j] + b_hh[q * 256 + j];
  }
}

// -------------------- main persistent kernel -------------------------------
__global__ __launch_bounds__(256) void rits_main(
    const float* __restrict__ values, const float* __restrict__ masks,
    const float* __restrict__ deltas, const float* __restrict__ evalm,
    const float* __restrict__ td_h_b, const float* __restrict__ td_x_w,
    const float* __restrict__ td_x_b, const float* __restrict__ hist_b,
    const float* __restrict__ feat_b, const float* __restrict__ wc_b,
    float* __restrict__ ws, float* __restrict__ out) {
  __shared__ float red[256];
  unsigned* cnt = reinterpret_cast<unsigned*>(ws);
  const int tid = threadIdx.x;
  const int bk = blockIdx.x;
  const int lane = tid & 63;
  const int wvu = __builtin_amdgcn_readfirstlane(tid >> 6);  // wave id, uniform
  const int mt = bk >> 4, nt = bk & 15;
  const int b0 = mt * 16;       // 16-row M-tile
  const int l8 = lane & 7;
  unsigned ep = 0;
  float lacc = 0.f;

  // ======================= P0: denom(t=bk), gamma_x(0) ======================
  {
    float s = 0.f;
    for (int i = tid; i < Bn * Dn; i += 256)
      s += evalm[(i >> 7) * LD + bk * Dn + (i & 127)];
    red[tid] = s;
    __syncthreads();
    for (int o = 128; o > 0; o >>= 1) {
      if (tid < o) red[tid] += red[tid + o];
      __syncthreads();
    }
    if (tid == 0) ws[OFF_DEN + bk] = red[0] + 1e-5f;
    if (tid < Dn) {
      float dv = deltas[bk * LD + tid];  // t = 0
      ws[OFF_GX + bk * Dn + tid] =
          expf(-fmaxf(dv * td_x_w[tid] + td_x_b[tid], 0.f));
    }
  }
  ep++; gridbar(cnt, ep * 256u);

  // ============================== time loop ================================
  for (int t = 0; t < Ln; ++t) {
    // ---- P2: gates_h (16r x 64c) + x_h/x_c (16r x 8c), K=256 over hd ----
    {
      const int gc = nt * 64 + lane;            // 0..1023 gate col
      const int jv = gc & 255, qv = gc >> 8;    // interleaved dest
      const int xc = nt * 8 + l8;               // 0..127 x col
      float ag0 = 0, ag1 = 0, ag2 = 0, ag3 = 0;
      float ax0 = 0, ax1 = 0, ax2 = 0, ax3 = 0;
      const float* hd0 = ws + OFF_HD + (b0 + wvu * 4) * Hn;
      const float* whh = ws + OFF_WHHT + gc;
      const float* hst = ws + OFF_HISTT + xc;
      for (int k = 0; k < Hn; k += 4) {
        const float4 a0 = *(const float4*)(hd0 + k);
        const float4 a1 = *(const float4*)(hd0 + Hn + k);
        const float4 a2 = *(const float4*)(hd0 + 2 * Hn + k);
        const float4 a3 = *(const float4*)(hd0 + 3 * Hn + k);
#pragma unroll
        for (int u = 0; u < 4; ++u) {
          float wg = whh[(k + u) * 1024];
          float wx = hst[(k + u) * 128];
          float e0 = (&a0.x)[u], e1 = (&a1.x)[u], e2 = (&a2.x)[u], e3 = (&a3.x)[u];
          ag0 += e0 * wg; ag1 += e1 * wg; ag2 += e2 * wg; ag3 += e3 * wg;
          ax0 += e0 * wx; ax1 += e1 * wx; ax2 += e2 * wx; ax3 += e3 * wx;
        }
      }
      const int r = b0 + wvu * 4;
      float* gh = ws + OFF_GH + jv * 4 + qv;
      gh[(r + 0) * 1024] = ag0; gh[(r + 1) * 1024] = ag1;
      gh[(r + 2) * 1024] = ag2; gh[(r + 3) * 1024] = ag3;
      if (lane < 8) {
        float hb = hist_b[xc];
        float axs[4] = {ax0, ax1, ax2, ax3};
#pragma unroll
        for (int i2 = 0; i2 < 4; ++i2) {
          int b = r + i2;
          int gi = b * LD + t * Dn + xc;
          float xh = axs[i2] + hb;
          float mm = masks[gi], xx = values[gi];
          ws[OFF_XH + b * Dn + xc] = xh;
          ws[OFF_XC + b * Dn + xc] = mm * xx + (1.f - mm) * xh;
        }
      }
      if (t == 0 && tid < Dn) {  // alpha(0), row bk (gamma_x(0) from P0)
        float acc = 0.f;
        const float* gx = ws + OFF_GX + bk * Dn;
        const float* mrow = masks + bk * LD;  // t=0
        for (int k = 0; k < Dn; ++k) acc += gx[k] * ws[OFF_WCT + k * Dn + tid];
        for (int k = 0; k < Dn; ++k)
          acc += mrow[k] * ws[OFF_WCT + (Dn + k) * Dn + tid];
        ws[OFF_AL + bk * Dn + tid] = acc + wc_b[tid];
      }
    }
    ep++; gridbar(cnt, ep * 256u);

    // ---- P3: z_h chain -> c_c, out, loss ; gamma_h/gamma_x(t+1) ----
    {
      const int zc = nt * 8 + l8;
      const int r = b0 + wvu * 4;
      float az0 = 0, az1 = 0, az2 = 0, az3 = 0;
      const float* xc0 = ws + OFF_XC + r * Dn;
      const float* wf = ws + OFF_WFT + zc;
      for (int k = 0; k < Dn; k += 4) {
        const float4 a0 = *(const float4*)(xc0 + k);
        const float4 a1 = *(const float4*)(xc0 + Dn + k);
        const float4 a2 = *(const float4*)(xc0 + 2 * Dn + k);
        const float4 a3 = *(const float4*)(xc0 + 3 * Dn + k);
#pragma unroll
        for (int u = 0; u < 4; ++u) {
          float w = wf[(k + u) * 128];
          az0 += (&a0.x)[u] * w; az1 += (&a1.x)[u] * w;
          az2 += (&a2.x)[u] * w; az3 += (&a3.x)[u] * w;
        }
      }
      if (lane < 8) {
        float fb = feat_b[zc];
        float rden = 1.f / ws[OFF_DEN + t];
        float azs[4] = {az0, az1, az2, az3};
#pragma unroll
        for (int i2 = 0; i2 < 4; ++i2) {
          int b = r + i2;
          int gi = b * LD + t * Dn + zc;
          float zh = azs[i2] + fb;
          float al = ws[OFF_AL + b * Dn + zc];
          float xh = ws[OFF_XH + b * Dn + zc];
          float ch = al * zh + (1.f - al) * xh;
          float mm = masks[gi], xx = values[gi], me = evalm[gi];
          float cc = mm * xx + (1.f - mm) * ch;
          ws[OFF_CC + b * Dn + zc] = cc;
          out[gi] = cc;
          lacc += fabsf(cc - xx) * me * rden;
        }
      }
      if (t + 1 < Ln) {  // gamma_h(t+1), gamma_x(t+1): row bk (input-only)
        const float* drow = deltas + bk * LD + (t + 1) * Dn;
        float acc = 0.f;
        for (int k = 0; k < Dn; ++k) acc += drow[k] * ws[OFF_TDHT + k * Hn + tid];
        ws[OFF_G + bk * Hn + tid] = expf(-fmaxf(acc + td_h_b[tid], 0.f));
        if (tid < Dn) {
          float dv = drow[tid];
          ws[OFF_GX + bk * Dn + tid] =
              expf(-fmaxf(dv * td_x_w[tid] + td_x_b[tid], 0.f));
        }
      }
    }
    ep++; gridbar(cnt, ep * 256u);

    // ---- P4: gates + LSTM -> c, hd(decayed) ; alpha(t+1) ----
    {
      const int rloc = lane >> 4, jj = lane & 15;
      const int j = nt * 16 + jj;
      const int b = b0 + wvu * 4 + rloc;
      float g0 = 0, g1 = 0, g2 = 0, g3 = 0;
      const float* ccrow = ws + OFF_CC + b * Dn;
      const float* mrow = masks + b * LD + t * Dn;
      const float* w4 = ws + OFF_W4 + j * 4;
      for (int k = 0; k < Dn; k += 4) {
        const float4 a = *(const float4*)(ccrow + k);
#pragma unroll
        for (int u = 0; u < 4; ++u) {
          const float4 w = *(const float4*)(w4 + (k + u) * 1024);
          float av = (&a.x)[u];
          g0 += av * w.x; g1 += av * w.y; g2 += av * w.z; g3 += av * w.w;
        }
      }
      for (int k = 0; k < Dn; k += 4) {
        const float4 a = *(const float4*)(mrow + k);
#pragma unroll
        for (int u = 0; u < 4; ++u) {
          const float4 w = *(const float4*)(w4 + (Dn + k + u) * 1024);
          float av = (&a.x)[u];
          g0 += av * w.x; g1 += av * w.y; g2 += av * w.z; g3 += av * w.w;
        }
      }
      const float4 bb = *(const float4*)(ws + OFF_B4 + j * 4);
      const float4 gh = *(const float4*)(ws + OFF_GH + b * 1024 + j * 4);
      g0 += bb.x + gh.x; g1 += bb.y + gh.y;
      g2 += bb.z + gh.z; g3 += bb.w + gh.w;
      float ig = 1.f / (1.f + expf(-g0));
      float fg = 1.f / (1.f + expf(-g1));
      float gg = tanhf(g2);
      float og = 1.f / (1.f + expf(-g3));
      float cold = ws[OFF_C + b * Hn + j];
      float cnew = fg * cold + ig * gg;
      ws[OFF_C + b * Hn + j] = cnew;
      if (t + 1 < Ln) {  // store h pre-decayed with gamma_h(t+1) (from P3)
        float gn = ws[OFF_G + b * Hn + j];
        ws[OFF_HD + b * Hn + j] = og * tanhf(cnew) * gn;
      }
      if (t + 1 < Ln && tid < Dn) {  // alpha(t+1), row bk (gamma_x from P3)
        float acc2 = 0.f;
        const float* gx = ws + OFF_GX + bk * Dn;
        const float* mr2 = masks + bk * LD + (t + 1) * Dn;
        for (int k = 0; k < Dn; ++k) acc2 += gx[k] * ws[OFF_WCT + k * Dn + tid];
        for (int k = 0; k < Dn; ++k)
          acc2 += mr2[k] * ws[OFF_WCT + (Dn + k) * Dn + tid];
        ws[OFF_AL + bk * Dn + tid] = acc2 + wc_b[tid];
      }
    }
    ep++; gridbar(cnt, ep * 256u);
  }

  // ======================= loss reduce + final write =======================
  red[tid] = lacc;
  __syncthreads();
  for (int o = 128; o > 0; o >>= 1) {
    if (tid < o) red[tid] += red[tid + o];
    __syncthreads();
  }
  if (tid == 0) atomicAdd(ws + OFF_LOSS, red[0]);
  ep++; gridbar(cnt, ep * 256u);
  if (bk == 0 && tid == 0)
    out[Bn * LD] =
        __hip_atomic_load(ws + OFF_LOSS, __ATOMIC_RELAXED, __HIP_MEMORY_SCOPE_AGENT);
}

// -------------------- launcher ---------------------------------------------
extern "C" void kernel_launch(void* const* d_in, const int* in_sizes, int n_in,
                              void* d_out, int out_size, void* d_ws,
                              size_t ws_size, hipStream_t stream) {
  const float* values = (const float*)d_in[0];
  const float* masks = (const float*)d_in[1];
  const float* deltas = (const float*)d_in[2];
  const float* evalm = (const float*)d_in[3];
  const float* td_h_W = (const float*)d_in[4];
  const float* td_h_b = (const float*)d_in[5];
  const float* td_x_w = (const float*)d_in[6];
  const float* td_x_b = (const float*)d_in[7];
  const float* hist_W = (const float*)d_in[8];
  const float* hist_b = (const float*)d_in[9];
  const float* feat_W = (const float*)d_in[10];
  const float* feat_b = (const float*)d_in[11];
  const float* wc_W = (const float*)d_in[12];
  const float* wc_b = (const float*)d_in[13];
  const float* W_ih = (const float*)d_in[14];
  const float* W_hh = (const float*)d_in[15];
  const float* b_ih = (const float*)d_in[16];
  const float* b_hh = (const float*)d_in[17];
  float* ws = (float*)d_ws;
  float* out = (float*)d_out;

  // zero barrier counter, loss accumulator, hd(=h0*gamma=0), c0
  hipMemsetAsync(d_ws, 0, (size_t)ZERO_FLOATS * sizeof(float), stream);
  hipLaunchKernelGGL(rits_prep, dim3(2500), dim3(256), 0, stream, td_h_W, wc_W,
                     hist_W, feat_W, W_ih, W_hh, b_ih, b_hh, ws);
  hipLaunchKernelGGL(rits_main, dim3(256), dim3(256), 0, stream, values, masks,
                     deltas, evalm, td_h_b, td_x_w, td_x_b, hist_b, feat_b,
                     wc_b, ws, out);
}